// Round 1
// baseline (762.756 us; speedup 1.0000x reference)
//
#include <hip/hip_runtime.h>
#include <hip/hip_bf16.h>

// Problem: B=32, La=512, Lq=64, H=1024.
// Reassociated dataflow:
//   P1 = Q @ W1_1^T            [B,64,1024]   (flat GEMM 2048x1024x1024)
//   P2 = Q @ W1_2              [B,64,1024]
//   P3 = Q @ W2_1              [B,64,1024]
//   S1[b] = A[b] @ P1[b]^T     [B,512,64]  -> row softmax  = aq_attn
//   S2[b] = A[b] @ P2[b]^T     [B,512,64]  -> col softmax  = qa_attn [B,64,512]
//   PmaxA[b,mt,h] = colmax(relu(aq_attn[b] @ P3[b]))  (8 m-tiles of 64)
//   ctx[b] = qa_attn[b] @ A[b] [B,64,1024]
//   PmaxQ[b,h]    = colmax(relu(ctx_flat @ W2_2))     (m-tile == batch)
//   out[b,h] = 0.5*max_mt PmaxA + 0.5*PmaxQ

template<bool TRANSB, bool COLMAX>
__global__ __launch_bounds__(256) void gemm64(
    const float* __restrict__ A, const float* __restrict__ B, float* __restrict__ C,
    int M, int N, int K, long sA, long sB, long sC)
{
  const int b = blockIdx.z;
  const float* Ab = A + (long)b * sA;
  const float* Bb = B + (long)b * sB;
  const int m0 = blockIdx.y * 64;
  const int n0 = blockIdx.x * 64;
  const int t  = threadIdx.x;
  const int tx = t & 15, ty = t >> 4;

  __shared__ float As[16][65];   // As[k][m], +1 pad vs bank conflicts
  __shared__ float Bs[16][65];   // Bs[k][n]

  float acc[4][4] = {};

  for (int k0 = 0; k0 < K; k0 += 16) {
    #pragma unroll
    for (int i = 0; i < 4; ++i) {          // A tile: 64x16
      int e = t + i * 256;
      int m = e >> 4, kk = e & 15;
      As[kk][m] = Ab[(long)(m0 + m) * K + (k0 + kk)];
    }
    if (TRANSB) {                          // B is [N,K] row-major
      #pragma unroll
      for (int i = 0; i < 4; ++i) {
        int e = t + i * 256;
        int n = e >> 4, kk = e & 15;
        Bs[kk][n] = Bb[(long)(n0 + n) * K + (k0 + kk)];
      }
    } else {                               // B is [K,N] row-major, ld == N
      #pragma unroll
      for (int i = 0; i < 4; ++i) {
        int e = t + i * 256;
        int kk = e >> 6, n = e & 63;
        Bs[kk][n] = Bb[(long)(k0 + kk) * N + (n0 + n)];
      }
    }
    __syncthreads();
    #pragma unroll
    for (int kk = 0; kk < 16; ++kk) {
      float a[4], bv[4];
      #pragma unroll
      for (int i = 0; i < 4; ++i) a[i] = As[kk][ty * 4 + i];
      #pragma unroll
      for (int j = 0; j < 4; ++j) bv[j] = Bs[kk][tx * 4 + j];
      #pragma unroll
      for (int i = 0; i < 4; ++i)
        #pragma unroll
        for (int j = 0; j < 4; ++j)
          acc[i][j] = fmaf(a[i], bv[j], acc[i][j]);
    }
    __syncthreads();
  }

  if (COLMAX) {
    // relu + column max over this 64-row tile; one row of output per tile.
    __shared__ float cm[16][64];
    #pragma unroll
    for (int j = 0; j < 4; ++j) {
      float pm = 0.0f;                       // relu floor: max(0, .)
      #pragma unroll
      for (int i = 0; i < 4; ++i) pm = fmaxf(pm, acc[i][j]);
      cm[ty][tx * 4 + j] = pm;
    }
    __syncthreads();
    if (t < 64) {
      float m = 0.0f;
      #pragma unroll
      for (int r = 0; r < 16; ++r) m = fmaxf(m, cm[r][t]);
      C[((long)blockIdx.z * gridDim.y + blockIdx.y) * N + n0 + t] = m;
    }
  } else {
    float* Cb = C + (long)b * sC;
    #pragma unroll
    for (int i = 0; i < 4; ++i)
      #pragma unroll
      for (int j = 0; j < 4; ++j)
        Cb[(long)(m0 + ty * 4 + i) * N + (n0 + tx * 4 + j)] = acc[i][j];
  }
}

// In-place row softmax, rows of length 64 (one wave per row).
__global__ __launch_bounds__(256) void softmax_rows64(float* __restrict__ S, int nrows)
{
  int row  = blockIdx.x * 4 + (threadIdx.x >> 6);
  int lane = threadIdx.x & 63;
  if (row >= nrows) return;
  float v = S[(long)row * 64 + lane];
  float m = v;
  #pragma unroll
  for (int off = 32; off; off >>= 1) m = fmaxf(m, __shfl_xor(m, off));
  float e = __expf(v - m);
  float s = e;
  #pragma unroll
  for (int off = 32; off; off >>= 1) s += __shfl_xor(s, off);
  S[(long)row * 64 + lane] = e / s;
}

// qa_attn[b,q,a] = softmax over a (=512) of S2[b,a,q]. One block per (b,q).
__global__ __launch_bounds__(256) void softmax_cols_k(
    const float* __restrict__ S2, float* __restrict__ qa)
{
  int bq = blockIdx.x;            // b*64 + q
  int b = bq >> 6, q = bq & 63;
  int t = threadIdx.x;
  const float* base = S2 + (long)b * 512 * 64 + q;
  float v0 = base[(long)t * 64];
  float v1 = base[(long)(t + 256) * 64];
  float m = fmaxf(v0, v1);
  #pragma unroll
  for (int off = 32; off; off >>= 1) m = fmaxf(m, __shfl_xor(m, off));
  __shared__ float sm[4], ss[4];
  int wid = t >> 6, lane = t & 63;
  if (lane == 0) sm[wid] = m;
  __syncthreads();
  float M = fmaxf(fmaxf(sm[0], sm[1]), fmaxf(sm[2], sm[3]));
  float e0 = __expf(v0 - M), e1 = __expf(v1 - M);
  float s = e0 + e1;
  #pragma unroll
  for (int off = 32; off; off >>= 1) s += __shfl_xor(s, off);
  if (lane == 0) ss[wid] = s;
  __syncthreads();
  float inv = 1.0f / ((ss[0] + ss[1]) + (ss[2] + ss[3]));
  float* dst = qa + (long)bq * 512;
  dst[t]       = e0 * inv;
  dst[t + 256] = e1 * inv;
}

__global__ __launch_bounds__(256) void final_combine(
    const float* __restrict__ PmaxA, const float* __restrict__ PmaxQ, float* __restrict__ out)
{
  int idx = blockIdx.x * 256 + threadIdx.x;   // 32768 = 32*1024
  int b = idx >> 10, h = idx & 1023;
  float m = 0.0f;
  #pragma unroll
  for (int mt = 0; mt < 8; ++mt)
    m = fmaxf(m, PmaxA[((long)(b * 8 + mt)) * 1024 + h]);
  out[idx] = 0.5f * m + 0.5f * PmaxQ[idx];
}

extern "C" void kernel_launch(void* const* d_in, const int* in_sizes, int n_in,
                              void* d_out, int out_size, void* d_ws, size_t ws_size,
                              hipStream_t stream) {
  const float* Afeat = (const float*)d_in[0];  // [32,512,1024]
  const float* Qfeat = (const float*)d_in[1];  // [32,64,1024]
  const float* W11   = (const float*)d_in[2];
  const float* W12   = (const float*)d_in[3];
  const float* W21   = (const float*)d_in[4];
  const float* W22   = (const float*)d_in[5];
  float* out = (float*)d_out;

  float* ws    = (float*)d_ws;
  float* P1    = ws;                 // 2,097,152
  float* P2    = P1 + 2097152;       // 2,097,152
  float* P3    = P2 + 2097152;       // 2,097,152
  float* S1    = P3 + 2097152;       // 1,048,576 (becomes aq_attn in-place)
  float* S2    = S1 + 1048576;       // 1,048,576
  float* qa    = S2 + 1048576;       // 1,048,576
  float* ctx   = qa + 1048576;       // 2,097,152
  float* PmaxA = ctx + 2097152;      //   262,144
  float* PmaxQ = PmaxA + 262144;     //    32,768   (total ~47.3 MB)

  dim3 blk(256);

  // P1 = Qflat @ W1_1^T ; P2 = Qflat @ W1_2 ; P3 = Qflat @ W2_1   (M=2048,N=1024,K=1024)
  gemm64<true,  false><<<dim3(16, 32, 1), blk, 0, stream>>>(Qfeat, W11, P1, 2048, 1024, 1024, 0, 0, 0);
  gemm64<false, false><<<dim3(16, 32, 1), blk, 0, stream>>>(Qfeat, W12, P2, 2048, 1024, 1024, 0, 0, 0);
  gemm64<false, false><<<dim3(16, 32, 1), blk, 0, stream>>>(Qfeat, W21, P3, 2048, 1024, 1024, 0, 0, 0);

  // S1[b] = A[b] @ P1[b]^T ; S2[b] = A[b] @ P2[b]^T   (M=512,N=64,K=1024, batched)
  gemm64<true, false><<<dim3(1, 8, 32), blk, 0, stream>>>(Afeat, P1, S1, 512, 64, 1024,
                                                          512L * 1024, 64L * 1024, 512L * 64);
  gemm64<true, false><<<dim3(1, 8, 32), blk, 0, stream>>>(Afeat, P2, S2, 512, 64, 1024,
                                                          512L * 1024, 64L * 1024, 512L * 64);

  softmax_rows64<<<dim3(4096), blk, 0, stream>>>(S1, 16384);     // aq_attn (in-place)
  softmax_cols_k<<<dim3(2048), blk, 0, stream>>>(S2, qa);        // qa_attn [B,64,512]

  // PmaxA[b*8+mt, h] = colmax(relu(aq_attn[b] @ P3[b]))   (M=512,N=1024,K=64)
  gemm64<false, true><<<dim3(16, 8, 32), blk, 0, stream>>>(S1, P3, PmaxA, 512, 1024, 64,
                                                           512L * 64, 64L * 1024, 0);

  // ctx[b] = qa_attn[b] @ A[b]   (M=64,N=1024,K=512)
  gemm64<false, false><<<dim3(16, 1, 32), blk, 0, stream>>>(qa, Afeat, ctx, 64, 1024, 512,
                                                            64L * 512, 512L * 1024, 64L * 1024);

  // PmaxQ[b, h] = colmax(relu(ctx_flat @ W2_2))   (M=2048,N=1024,K=1024; m-tile == batch)
  gemm64<false, true><<<dim3(16, 32, 1), blk, 0, stream>>>(ctx, W22, PmaxQ, 2048, 1024, 1024, 0, 0, 0);

  final_combine<<<dim3(128), blk, 0, stream>>>(PmaxA, PmaxQ, out);
}

// Round 2
// 225.273 us; speedup vs baseline: 3.3859x; 3.3859x over previous
//
#include <hip/hip_runtime.h>
#include <stdint.h>

// B=32, La=512, Lq=64, H=1024.
// Score path in split-bf16 (hi+lo, 3 MFMA) for ~fp32 precision; value path plain bf16.
//   Pcat[b]   = [P1[b];P2[b]]  : split GEMM  Q(split) @ [W11; W12^T]^T  (M=2048,N=2048,K=1024)
//   Spack[b]  = A[b](split) @ Pcat[b]^T     (M=512,N=128,K=1024)  fp32 scores
//   aq = rowsoftmax(Spack[:, :64])  bf16 ; qa = colsoftmax(Spack[:, 64:]) bf16
//   P3T[b][h][q] = (Q @ W21)^T   bf16      (plain GEMM, transposed epilogue)
//   PmaxA[b*4+mt][h] = colmax(relu(aq[b] @ P3T[b]^T))       (K=64)
//   ctx[b] = qa[b] @ AT[b]^T     bf16      (M=64,N=1024,K=512)
//   PmaxQ[b][h] = colmax64(relu(ctx @ W22T^T))
//   out = 0.5*max_mt(PmaxA) + 0.5*PmaxQ

using bf16x8 = __attribute__((ext_vector_type(8))) short;
using f32x4  = __attribute__((ext_vector_type(4))) float;
typedef const __attribute__((address_space(1))) void* gas_t;
typedef __attribute__((address_space(3))) void* las_t;

__device__ __forceinline__ unsigned short f2bf(float x) {
  unsigned u = __builtin_bit_cast(unsigned, x);
  u += 0x7fffu + ((u >> 16) & 1u);
  return (unsigned short)(u >> 16);
}
__device__ __forceinline__ float bf2f(unsigned short h) {
  unsigned u = ((unsigned)h) << 16;
  return __builtin_bit_cast(float, u);
}

// ---------------- prep kernels ----------------

__global__ __launch_bounds__(256) void conv_split(const float* __restrict__ in,
    unsigned short* __restrict__ hi, unsigned short* __restrict__ lo, int n4)
{
  int i = blockIdx.x * 256 + threadIdx.x;
  if (i >= n4) return;
  float4 v = ((const float4*)in)[i];
  ushort4 h, l;
  h.x = f2bf(v.x); l.x = f2bf(v.x - bf2f(h.x));
  h.y = f2bf(v.y); l.y = f2bf(v.y - bf2f(h.y));
  h.z = f2bf(v.z); l.z = f2bf(v.z - bf2f(h.z));
  h.w = f2bf(v.w); l.w = f2bf(v.w - bf2f(h.w));
  ((ushort4*)hi)[i] = h;
  ((ushort4*)lo)[i] = l;
}

// in [z][R][C] fp32 -> out [z][C][R] bf16 (hi, and lo if SPLIT)
template<bool SPLIT>
__global__ __launch_bounds__(256) void transpose_conv(const float* __restrict__ in,
    unsigned short* __restrict__ hi, unsigned short* __restrict__ lo, int R, int C)
{
  __shared__ float tile[32][33];
  long boff = (long)blockIdx.z * R * C;
  int r0 = blockIdx.y * 32, c0 = blockIdx.x * 32;
  int tx = threadIdx.x, ty = threadIdx.y;
  #pragma unroll
  for (int i = 0; i < 4; ++i)
    tile[ty + i * 8][tx] = in[boff + (long)(r0 + ty + i * 8) * C + c0 + tx];
  __syncthreads();
  #pragma unroll
  for (int i = 0; i < 4; ++i) {
    float v = tile[tx][ty + i * 8];
    long o = boff + (long)(c0 + ty + i * 8) * R + r0 + tx;
    unsigned short h = f2bf(v);
    hi[o] = h;
    if (SPLIT) lo[o] = f2bf(v - bf2f(h));
  }
}

// ---------------- MFMA GEMM (C = A @ B^T), 128x128 tile, BK=32 ----------------
// OUT: 0=f32 (ldC), 1=split remap to Pcat, 2=bf16 (ldC, row<M), 3=per-batch transpose (P3T),
//      4=relu+colmax group128, 5=relu+colmax group64
template<bool SPLIT, int OUT>
__global__ __launch_bounds__(256) void gemm_mfma(
    const unsigned short* __restrict__ Ah, const unsigned short* __restrict__ Al,
    const unsigned short* __restrict__ Bh, const unsigned short* __restrict__ Bl,
    float* __restrict__ Cf, unsigned short* __restrict__ Ch, unsigned short* __restrict__ Cl,
    int M, int N, int K, int ldA, int ldB, int ldC, long sA, long sB, long sC)
{
  constexpr int SMEM = SPLIT ? 32768 : 20480;
  __shared__ char smem[SMEM];
  char* As  = smem;
  char* Asl = SPLIT ? smem + 8192 : nullptr;
  char* Bs  = SPLIT ? smem + 16384 : smem + 8192;
  char* Bsl = SPLIT ? smem + 24576 : nullptr;

  const int z  = blockIdx.z;
  const int m0 = blockIdx.y * 128;
  const int n0 = blockIdx.x * 128;
  const int t  = threadIdx.x;
  const int lane = t & 63;
  const int wid  = t >> 6;
  const int wr = wid >> 1, wc = wid & 1;

  const unsigned short* Ab  = Ah + (long)z * sA;
  const unsigned short* Bb  = Bh + (long)z * sB;
  const unsigned short* Abl = SPLIT ? Al + (long)z * sA : nullptr;
  const unsigned short* Bbl = SPLIT ? Bl + (long)z * sB : nullptr;

  f32x4 acc[4][4];
  #pragma unroll
  for (int i = 0; i < 4; ++i)
    #pragma unroll
    for (int j = 0; j < 4; ++j)
      acc[i][j] = f32x4{0.f, 0.f, 0.f, 0.f};

  // stage 8KB: LDS linear dest, inverse-swizzled global source (swz is an involution)
  auto stage = [&](char* lbuf, const unsigned short* g, int ld, int base0, int k0, int mmax) {
    #pragma unroll
    for (int i = 0; i < 2; ++i) {
      int ob = i * 4096 + t * 16;
      int e  = ob ^ (((ob >> 7) & 3) << 4);
      int m  = e >> 6, k = (e & 63) >> 1;
      int row = base0 + m; row = row < mmax ? row : mmax - 1;
      const unsigned short* gp = g + (long)row * ld + k0 + k;
      char* lp = lbuf + i * 4096 + (t & ~63) * 16;  // wave-uniform; HW adds lane*16
      __builtin_amdgcn_global_load_lds((gas_t)(const void*)gp, (las_t)(void*)lp, 16, 0, 0);
    }
  };
  auto ldfrag = [&](const char* lbuf, int rrow) -> bf16x8 {
    int ob = rrow * 64 + (lane >> 4) * 16;
    ob ^= ((ob >> 7) & 3) << 4;
    return *(const bf16x8*)(lbuf + ob);
  };

  for (int k0 = 0; k0 < K; k0 += 32) {
    stage(As, Ab, ldA, m0, k0, M);
    stage(Bs, Bb, ldB, n0, k0, N);
    if (SPLIT) {
      stage(Asl, Abl, ldA, m0, k0, M);
      stage(Bsl, Bbl, ldB, n0, k0, N);
    }
    __syncthreads();

    bf16x8 ah[4], al[4];
    #pragma unroll
    for (int mi = 0; mi < 4; ++mi) {
      int rr = wr * 64 + mi * 16 + (lane & 15);
      ah[mi] = ldfrag(As, rr);
      if (SPLIT) al[mi] = ldfrag(Asl, rr);
    }
    #pragma unroll
    for (int ni = 0; ni < 4; ++ni) {
      int rc = wc * 64 + ni * 16 + (lane & 15);
      bf16x8 bh = ldfrag(Bs, rc);
      bf16x8 bl;
      if (SPLIT) bl = ldfrag(Bsl, rc);
      #pragma unroll
      for (int mi = 0; mi < 4; ++mi) {
        acc[mi][ni] = __builtin_amdgcn_mfma_f32_16x16x32_bf16(ah[mi], bh, acc[mi][ni], 0, 0, 0);
        if (SPLIT) {
          acc[mi][ni] = __builtin_amdgcn_mfma_f32_16x16x32_bf16(ah[mi], bl, acc[mi][ni], 0, 0, 0);
          acc[mi][ni] = __builtin_amdgcn_mfma_f32_16x16x32_bf16(al[mi], bh, acc[mi][ni], 0, 0, 0);
        }
      }
    }
    __syncthreads();
  }

  if (OUT == 4 || OUT == 5) {
    float* red = (float*)(smem + 16384);  // [8][128]
    #pragma unroll
    for (int ni = 0; ni < 4; ++ni) {
      float pm = 0.0f;  // relu floor
      #pragma unroll
      for (int mi = 0; mi < 4; ++mi)
        #pragma unroll
        for (int r = 0; r < 4; ++r)
          pm = fmaxf(pm, acc[mi][ni][r]);
      int g = wr * 4 + (lane >> 4);
      int col = wc * 64 + ni * 16 + (lane & 15);
      red[g * 128 + col] = pm;
    }
    __syncthreads();
    if (OUT == 4) {
      if (t < 128) {
        float m = red[t];
        #pragma unroll
        for (int g = 1; g < 8; ++g) m = fmaxf(m, red[g * 128 + t]);
        long orow = ((long)z * M + m0) >> 7;
        Cf[orow * ldC + n0 + t] = m;
      }
    } else {
      int hh = t >> 7, col = t & 127;
      float m = red[(hh * 4) * 128 + col];
      #pragma unroll
      for (int g = 1; g < 4; ++g) m = fmaxf(m, red[(hh * 4 + g) * 128 + col]);
      long orow = (m0 >> 6) + hh;
      Cf[orow * ldC + n0 + col] = m;
    }
    return;
  }

  #pragma unroll
  for (int mi = 0; mi < 4; ++mi) {
    #pragma unroll
    for (int r = 0; r < 4; ++r) {
      int grow = m0 + wr * 64 + mi * 16 + (lane >> 4) * 4 + r;
      #pragma unroll
      for (int ni = 0; ni < 4; ++ni) {
        int gcol = n0 + wc * 64 + ni * 16 + (lane & 15);
        float v = acc[mi][ni][r];
        if (OUT == 0) {
          Cf[(long)z * sC + (long)grow * ldC + gcol] = v;
        } else if (OUT == 1) {
          int b = grow >> 6, q = grow & 63;
          long dst = (long)b * 131072 + (long)((gcol >> 10) * 64 + q) * 1024 + (gcol & 1023);
          unsigned short h = f2bf(v);
          Ch[dst] = h;
          Cl[dst] = f2bf(v - bf2f(h));
        } else if (OUT == 2) {
          if (grow < M) Ch[(long)z * sC + (long)grow * ldC + gcol] = f2bf(v);
        } else if (OUT == 3) {
          long dst = (long)(grow >> 6) * 65536 + (long)gcol * 64 + (grow & 63);
          Ch[dst] = f2bf(v);
        }
      }
    }
  }
}

// ---------------- softmax ----------------

// rows of 64 from Spack[row][0..64), stride 128 -> aq bf16 [row][64]
__global__ __launch_bounds__(256) void softmax_rows(const float* __restrict__ S,
                                                    unsigned short* __restrict__ aq)
{
  int row  = blockIdx.x * 4 + (threadIdx.x >> 6);
  int lane = threadIdx.x & 63;
  float v = S[(long)row * 128 + lane];
  float m = v;
  #pragma unroll
  for (int off = 32; off; off >>= 1) m = fmaxf(m, __shfl_xor(m, off));
  float e = __expf(v - m);
  float s = e;
  #pragma unroll
  for (int off = 32; off; off >>= 1) s += __shfl_xor(s, off);
  aq[(long)row * 64 + lane] = f2bf(e / s);
}

// softmax over a=512 of Spack[b][a][64+q] -> qa bf16 [b][q][512]
__global__ __launch_bounds__(256) void softmax_cols(const float* __restrict__ S,
                                                    unsigned short* __restrict__ qa)
{
  int bq = blockIdx.x;
  int b = bq >> 6, q = bq & 63;
  int t = threadIdx.x;
  const float* base = S + (long)b * 512 * 128 + 64 + q;
  float v0 = base[(long)t * 128];
  float v1 = base[(long)(t + 256) * 128];
  float m = fmaxf(v0, v1);
  #pragma unroll
  for (int off = 32; off; off >>= 1) m = fmaxf(m, __shfl_xor(m, off));
  __shared__ float sm[4], ss[4];
  int wid = t >> 6, lane = t & 63;
  if (lane == 0) sm[wid] = m;
  __syncthreads();
  float M = fmaxf(fmaxf(sm[0], sm[1]), fmaxf(sm[2], sm[3]));
  float e0 = __expf(v0 - M), e1 = __expf(v1 - M);
  float s = e0 + e1;
  #pragma unroll
  for (int off = 32; off; off >>= 1) s += __shfl_xor(s, off);
  if (lane == 0) ss[wid] = s;
  __syncthreads();
  float inv = 1.0f / ((ss[0] + ss[1]) + (ss[2] + ss[3]));
  qa[(long)bq * 512 + t]       = f2bf(e0 * inv);
  qa[(long)bq * 512 + t + 256] = f2bf(e1 * inv);
}

__global__ __launch_bounds__(256) void final_combine(
    const float* __restrict__ PmaxA, const float* __restrict__ PmaxQ, float* __restrict__ out)
{
  int idx = blockIdx.x * 256 + threadIdx.x;  // 32768
  int b = idx >> 10, h = idx & 1023;
  float m = PmaxA[(long)(b * 4) * 1024 + h];
  #pragma unroll
  for (int mt = 1; mt < 4; ++mt)
    m = fmaxf(m, PmaxA[(long)(b * 4 + mt) * 1024 + h]);
  out[idx] = 0.5f * m + 0.5f * PmaxQ[idx];
}

// ---------------- launch ----------------

extern "C" void kernel_launch(void* const* d_in, const int* in_sizes, int n_in,
                              void* d_out, int out_size, void* d_ws, size_t ws_size,
                              hipStream_t stream) {
  const float* Afeat = (const float*)d_in[0];  // [32,512,1024]
  const float* Qfeat = (const float*)d_in[1];  // [32,64,1024]
  const float* W11   = (const float*)d_in[2];
  const float* W12   = (const float*)d_in[3];
  const float* W21   = (const float*)d_in[4];
  const float* W22   = (const float*)d_in[5];
  float* out = (float*)d_out;

  char* w = (char*)d_ws;
  auto alloc = [&](long bytes) { char* p = w; w += bytes; return p; };
  unsigned short* A_hi    = (unsigned short*)alloc(33554432);
  unsigned short* A_lo    = (unsigned short*)alloc(33554432);
  unsigned short* AT      = (unsigned short*)alloc(33554432);  // [32][1024][512]
  unsigned short* Q_hi    = (unsigned short*)alloc(4194304);
  unsigned short* Q_lo    = (unsigned short*)alloc(4194304);
  unsigned short* Wcat_hi = (unsigned short*)alloc(4194304);   // [2048][1024]: W11 ; W12^T
  unsigned short* Wcat_lo = (unsigned short*)alloc(4194304);
  unsigned short* W21T    = (unsigned short*)alloc(2097152);
  unsigned short* W22T    = (unsigned short*)alloc(2097152);
  unsigned short* Pcat_hi = (unsigned short*)alloc(8388608);   // [32][128][1024]
  unsigned short* Pcat_lo = (unsigned short*)alloc(8388608);
  unsigned short* P3T     = (unsigned short*)alloc(4194304);   // [32][1024][64]
  float*          Spack   = (float*)alloc(8388608);            // [32][512][128]
  unsigned short* aq      = (unsigned short*)alloc(2097152);   // [32][512][64]
  unsigned short* qa      = (unsigned short*)alloc(2097152);   // [32][64][512]
  unsigned short* ctx     = (unsigned short*)alloc(4194304);   // [32][64][1024]
  float*          PmaxA   = (float*)alloc(524288);             // [128][1024]
  float*          PmaxQ   = (float*)alloc(131072);             // [32][1024]

  dim3 blk(256), tblk(32, 8);

  conv_split<<<16384, blk, 0, stream>>>(Afeat, A_hi, A_lo, 4194304);
  conv_split<<<2048,  blk, 0, stream>>>(Qfeat, Q_hi, Q_lo, 524288);
  conv_split<<<1024,  blk, 0, stream>>>(W11, Wcat_hi, Wcat_lo, 262144);
  transpose_conv<true ><<<dim3(32, 32, 1),  tblk, 0, stream>>>(W12, Wcat_hi + 1048576, Wcat_lo + 1048576, 1024, 1024);
  transpose_conv<false><<<dim3(32, 32, 1),  tblk, 0, stream>>>(W21, W21T, nullptr, 1024, 1024);
  transpose_conv<false><<<dim3(32, 32, 1),  tblk, 0, stream>>>(W22, W22T, nullptr, 1024, 1024);
  transpose_conv<false><<<dim3(32, 16, 32), tblk, 0, stream>>>(Afeat, AT, nullptr, 512, 1024);

  // Pcat = Q(split) @ Wcat^T, split epilogue with per-batch remap
  gemm_mfma<true, 1><<<dim3(16, 16, 1), blk, 0, stream>>>(
      Q_hi, Q_lo, Wcat_hi, Wcat_lo, nullptr, Pcat_hi, Pcat_lo,
      2048, 2048, 1024, 1024, 1024, 0, 0, 0, 0);

  // Spack[b] = A[b](split) @ Pcat[b]^T  (fp32 scores)
  gemm_mfma<true, 0><<<dim3(1, 4, 32), blk, 0, stream>>>(
      A_hi, A_lo, Pcat_hi, Pcat_lo, Spack, nullptr, nullptr,
      512, 128, 1024, 1024, 1024, 128, 512L * 1024, 128L * 1024, 512L * 128);

  softmax_rows<<<4096, blk, 0, stream>>>(Spack, aq);
  softmax_cols<<<2048, blk, 0, stream>>>(Spack, qa);

  // P3T = (Q @ W21)^T per batch, bf16
  gemm_mfma<false, 3><<<dim3(8, 16, 1), blk, 0, stream>>>(
      Q_hi, nullptr, W21T, nullptr, nullptr, P3T, nullptr,
      2048, 1024, 1024, 1024, 1024, 0, 0, 0, 0);

  // PmaxA[b*4+mt] = colmax(relu(aq[b] @ P3T[b]^T))
  gemm_mfma<false, 4><<<dim3(8, 4, 32), blk, 0, stream>>>(
      aq, nullptr, P3T, nullptr, PmaxA, nullptr, nullptr,
      512, 1024, 64, 64, 64, 1024, 512L * 64, 1024L * 64, 0);

  // ctx[b] = qa[b] @ AT[b]^T  (bf16)
  gemm_mfma<false, 2><<<dim3(8, 1, 32), blk, 0, stream>>>(
      qa, nullptr, AT, nullptr, nullptr, ctx, nullptr,
      64, 1024, 512, 512, 512, 1024, 64L * 512, 1024L * 512, 64L * 1024);

  // PmaxQ[b] = colmax64(relu(ctx @ W22T^T))
  gemm_mfma<false, 5><<<dim3(8, 16, 1), blk, 0, stream>>>(
      ctx, nullptr, W22T, nullptr, PmaxQ, nullptr, nullptr,
      2048, 1024, 1024, 1024, 1024, 1024, 0, 0, 0);

  final_combine<<<128, blk, 0, stream>>>(PmaxA, PmaxQ, out);
}

// Round 3
// 157.110 us; speedup vs baseline: 4.8549x; 1.4339x over previous
//
#include <hip/hip_runtime.h>
#include <stdint.h>

// B=32, La=512, Lq=64, H=1024. Score path split-bf16 (3 MFMA), value path bf16.
// G1: Pcat = Q(split)@Wcat^T (remapped)  ||  P3T = (Q@W21)^T
// G2: Spack[b] = A[b](split) @ Pcat[b]^T (fp32 scores)
// softmax_both: aq = rowsoftmax(Spack[:,:64]); qa = colsoftmax(Spack[:,64:])
// G3: PmaxA = colmax(relu(aq@P3T^T))  ||  ctx = qa@AT^T
// G4: PmaxQ = colmax64(relu(ctx@W22T^T))
// final: out = 0.5*max4(PmaxA) + 0.5*PmaxQ

using bf16x8 = __attribute__((ext_vector_type(8))) short;
using f32x4  = __attribute__((ext_vector_type(4))) float;
typedef const __attribute__((address_space(1))) void* gas_t;
typedef __attribute__((address_space(3))) void* las_t;

__device__ __forceinline__ unsigned short f2bf(float x) {
  unsigned u = __builtin_bit_cast(unsigned, x);
  u += 0x7fffu + ((u >> 16) & 1u);
  return (unsigned short)(u >> 16);
}
__device__ __forceinline__ float bf2f(unsigned short h) {
  unsigned u = ((unsigned)h) << 16;
  return __builtin_bit_cast(float, u);
}

// ---------------- generic MFMA GEMM body (C = A @ B^T) ----------------
// Tile BM x BN, BK=32, 4 waves in 2x2. OUT: 0=f32, 1=Pcat split remap,
// 2=bf16 (row<M), 3=P3T transpose, 4=relu+colmax(BM), 5=relu+colmax per 64 rows.
template<int BM, int BN, bool SPLIT, int OUT>
__device__ __forceinline__ void gemm_body(
    char* smem, int bx, int by, int z,
    const unsigned short* __restrict__ Ah, const unsigned short* __restrict__ Al,
    const unsigned short* __restrict__ Bh, const unsigned short* __restrict__ Bl,
    float* __restrict__ Cf, unsigned short* __restrict__ Ch, unsigned short* __restrict__ Cl,
    int M, int N, int K, int ldA, int ldB, int ldC, long sA, long sB, long sC, int mtiles)
{
  constexpr int MI = BM / 32, NI = BN / 32;
  constexpr int AB = BM * 64, BB = BN * 64;
  char* As  = smem;
  char* Asl = SPLIT ? smem + AB : nullptr;
  char* Bs  = smem + (SPLIT ? 2 * AB : AB);
  char* Bsl = SPLIT ? Bs + BB : nullptr;

  const int m0 = by * BM, n0 = bx * BN;
  const int t = threadIdx.x, lane = t & 63;
  const int wid = t >> 6, wr = wid >> 1, wc = wid & 1;

  const unsigned short* Ab  = Ah + (long)z * sA;
  const unsigned short* Bb  = Bh + (long)z * sB;
  const unsigned short* Abl = SPLIT ? Al + (long)z * sA : nullptr;
  const unsigned short* Bbl = SPLIT ? Bl + (long)z * sB : nullptr;

  f32x4 acc[MI][NI];
  #pragma unroll
  for (int i = 0; i < MI; ++i)
    #pragma unroll
    for (int j = 0; j < NI; ++j)
      acc[i][j] = f32x4{0.f, 0.f, 0.f, 0.f};

  // stage one 4KB chunk (64 rows x 64B): linear LDS dest, inverse-swizzled source
  auto stage4k = [&](char* lbuf, const unsigned short* g, int ld, int row0, int k0, int rmax) {
    int ob = t * 16;
    int e  = ob ^ (((ob >> 7) & 3) << 4);
    int m  = e >> 6, k = (e & 63) >> 1;
    int row = row0 + m; row = row < rmax ? row : rmax - 1;
    const unsigned short* gp = g + (long)row * ld + k0 + k;
    char* lp = lbuf + (t & ~63) * 16;  // wave-uniform; HW adds lane*16
    __builtin_amdgcn_global_load_lds((gas_t)(const void*)gp, (las_t)(void*)lp, 16, 0, 0);
  };
  auto ldfrag = [&](const char* lbuf, int rr) -> bf16x8 {
    int ob = rr * 64 + (lane >> 4) * 16;
    ob ^= ((ob >> 7) & 3) << 4;
    return *(const bf16x8*)(lbuf + ob);
  };

  for (int k0 = 0; k0 < K; k0 += 32) {
    stage4k(As, Ab, ldA, m0, k0, M);
    if (BM == 128) stage4k(As + 4096, Ab, ldA, m0 + 64, k0, M);
    stage4k(Bs, Bb, ldB, n0, k0, N);
    if (BN == 128) stage4k(Bs + 4096, Bb, ldB, n0 + 64, k0, N);
    if (SPLIT) {
      stage4k(Asl, Abl, ldA, m0, k0, M);
      if (BM == 128) stage4k(Asl + 4096, Abl, ldA, m0 + 64, k0, M);
      stage4k(Bsl, Bbl, ldB, n0, k0, N);
      if (BN == 128) stage4k(Bsl + 4096, Bbl, ldB, n0 + 64, k0, N);
    }
    __syncthreads();

    bf16x8 ah[MI], al[MI];
    #pragma unroll
    for (int mi = 0; mi < MI; ++mi) {
      int rr = wr * (BM / 2) + mi * 16 + (lane & 15);
      ah[mi] = ldfrag(As, rr);
      if (SPLIT) al[mi] = ldfrag(Asl, rr);
    }
    #pragma unroll
    for (int ni = 0; ni < NI; ++ni) {
      int rc = wc * (BN / 2) + ni * 16 + (lane & 15);
      bf16x8 bh = ldfrag(Bs, rc);
      bf16x8 bl;
      if (SPLIT) bl = ldfrag(Bsl, rc);
      #pragma unroll
      for (int mi = 0; mi < MI; ++mi) {
        acc[mi][ni] = __builtin_amdgcn_mfma_f32_16x16x32_bf16(ah[mi], bh, acc[mi][ni], 0, 0, 0);
        if (SPLIT) {
          acc[mi][ni] = __builtin_amdgcn_mfma_f32_16x16x32_bf16(ah[mi], bl, acc[mi][ni], 0, 0, 0);
          acc[mi][ni] = __builtin_amdgcn_mfma_f32_16x16x32_bf16(al[mi], bh, acc[mi][ni], 0, 0, 0);
        }
      }
    }
    __syncthreads();
  }

  if (OUT == 4 || OUT == 5) {
    float* red = (float*)smem;  // safe: k-loop ended with __syncthreads
    #pragma unroll
    for (int ni = 0; ni < NI; ++ni) {
      float pm = 0.0f;  // relu floor
      #pragma unroll
      for (int mi = 0; mi < MI; ++mi)
        #pragma unroll
        for (int r = 0; r < 4; ++r)
          pm = fmaxf(pm, acc[mi][ni][r]);
      int g = wr * 4 + (lane >> 4);
      int col = wc * (BN / 2) + ni * 16 + (lane & 15);
      red[g * BN + col] = pm;
    }
    __syncthreads();
    if (OUT == 4) {
      if (t < BN) {
        float m = red[t];
        #pragma unroll
        for (int g = 1; g < 8; ++g) m = fmaxf(m, red[g * BN + t]);
        Cf[(long)(z * mtiles + by) * ldC + n0 + t] = m;
      }
    } else {
      constexpr int NGR = BM / 64, PG = 8 / NGR;
      if (t < NGR * BN) {
        int hh = t / BN, col = t - hh * BN;
        float m = red[(hh * PG) * BN + col];
        #pragma unroll
        for (int i = 1; i < PG; ++i) m = fmaxf(m, red[(hh * PG + i) * BN + col]);
        Cf[(long)((m0 >> 6) + hh) * ldC + n0 + col] = m;
      }
    }
    return;
  }

  #pragma unroll
  for (int mi = 0; mi < MI; ++mi) {
    #pragma unroll
    for (int r = 0; r < 4; ++r) {
      int grow = m0 + wr * (BM / 2) + mi * 16 + (lane >> 4) * 4 + r;
      #pragma unroll
      for (int ni = 0; ni < NI; ++ni) {
        int gcol = n0 + wc * (BN / 2) + ni * 16 + (lane & 15);
        float v = acc[mi][ni][r];
        if (OUT == 0) {
          Cf[(long)z * sC + (long)grow * ldC + gcol] = v;
        } else if (OUT == 1) {
          int b = grow >> 6, q = grow & 63;
          long dst = (long)b * 131072 + (long)((gcol >> 10) * 64 + q) * 1024 + (gcol & 1023);
          unsigned short h = f2bf(v);
          Ch[dst] = h;
          Cl[dst] = f2bf(v - bf2f(h));
        } else if (OUT == 2) {
          if (grow < M) Ch[(long)z * sC + (long)grow * ldC + gcol] = f2bf(v);
        } else if (OUT == 3) {
          long dst = (long)(grow >> 6) * 65536 + (long)gcol * 64 + (grow & 63);
          Ch[dst] = f2bf(v);
        }
      }
    }
  }
}

// ---------------- fat GEMM dispatches ----------------

__global__ __launch_bounds__(256) void g1_kernel(
    const unsigned short* Q_hi, const unsigned short* Q_lo,
    const unsigned short* Wcat_hi, const unsigned short* Wcat_lo,
    const unsigned short* W21T,
    unsigned short* Pcat_hi, unsigned short* Pcat_lo, unsigned short* P3T)
{
  __shared__ char smem[24576];
  int bid = blockIdx.x;
  if (bid < 512) {   // Pcat: M=2048,N=2048,K=1024, tile 128x64 -> 16x32
    gemm_body<128, 64, true, 1>(smem, bid & 31, bid >> 5, 0,
        Q_hi, Q_lo, Wcat_hi, Wcat_lo, nullptr, Pcat_hi, Pcat_lo,
        2048, 2048, 1024, 1024, 1024, 0, 0, 0, 0, 0);
  } else {           // P3T: M=2048,N=1024,K=1024, tile 64x64 -> 32x16
    int b2 = bid - 512;
    gemm_body<64, 64, false, 3>(smem, b2 & 15, b2 >> 4, 0,
        Q_hi, nullptr, W21T, nullptr, nullptr, P3T, nullptr,
        2048, 1024, 1024, 1024, 1024, 0, 0, 0, 0, 0);
  }
}

__global__ __launch_bounds__(256) void g2_kernel(
    const unsigned short* A_hi, const unsigned short* A_lo,
    const unsigned short* Pcat_hi, const unsigned short* Pcat_lo, float* Spack)
{
  __shared__ char smem[16384];
  gemm_body<64, 64, true, 0>(smem, blockIdx.x, blockIdx.y, blockIdx.z,
      A_hi, A_lo, Pcat_hi, Pcat_lo, Spack, nullptr, nullptr,
      512, 128, 1024, 1024, 1024, 128, 524288L, 131072L, 65536L, 0);
}

__global__ __launch_bounds__(256) void g3_kernel(
    const unsigned short* aq, const unsigned short* P3T, float* PmaxA,
    const unsigned short* qa, const unsigned short* AT, unsigned short* ctx)
{
  __shared__ char smem[16384];
  int bid = blockIdx.x;
  if (bid < 1024) {  // PmaxA: per batch M=512,N=1024,K=64, tile 128x128 -> (8,4,32)
    gemm_body<128, 128, false, 4>(smem, bid & 7, (bid >> 3) & 3, bid >> 5,
        aq, nullptr, P3T, nullptr, PmaxA, nullptr, nullptr,
        512, 1024, 64, 64, 64, 1024, 32768L, 65536L, 0, 4);
  } else {           // ctx: per batch M=64,N=1024,K=512, tile 64x64 -> (16,1,32)
    int b2 = bid - 1024;
    gemm_body<64, 64, false, 2>(smem, b2 & 15, 0, b2 >> 4,
        qa, nullptr, AT, nullptr, nullptr, ctx, nullptr,
        64, 1024, 512, 512, 512, 1024, 32768L, 524288L, 65536L, 0);
  }
}

__global__ __launch_bounds__(256) void g4_kernel(
    const unsigned short* ctx, const unsigned short* W22T, float* PmaxQ)
{
  __shared__ char smem[8192];
  gemm_body<64, 64, false, 5>(smem, blockIdx.x, blockIdx.y, 0,
      ctx, nullptr, W22T, nullptr, PmaxQ, nullptr, nullptr,
      2048, 1024, 1024, 1024, 1024, 1024, 0, 0, 0, 0);
}

// ---------------- prep ----------------

// z<32: A batch z -> A_hi/A_lo + AT. z>=32: Q pseudo-batch -> Q_hi/Q_lo.
__global__ __launch_bounds__(256) void prep_A(const float* __restrict__ A, const float* __restrict__ Q,
    unsigned short* __restrict__ A_hi, unsigned short* __restrict__ A_lo,
    unsigned short* __restrict__ AT,
    unsigned short* __restrict__ Q_hi, unsigned short* __restrict__ Q_lo)
{
  __shared__ float tile[32][33];
  int z = blockIdx.z;
  bool isQ = z >= 32;
  int zz = isQ ? z - 32 : z;
  const float* src = (isQ ? Q : A) + (long)zz * 524288;
  int r0 = blockIdx.y * 32, c0 = blockIdx.x * 32;
  int tx = threadIdx.x, ty = threadIdx.y;
  #pragma unroll
  for (int i = 0; i < 4; ++i) {
    int r = r0 + ty + i * 8;
    float v = src[(long)r * 1024 + c0 + tx];
    tile[ty + i * 8][tx] = v;
    unsigned short h = f2bf(v);
    long o = (long)zz * 524288 + (long)r * 1024 + c0 + tx;
    (isQ ? Q_hi : A_hi)[o] = h;
    (isQ ? Q_lo : A_lo)[o] = f2bf(v - bf2f(h));
  }
  __syncthreads();
  if (!isQ) {
    #pragma unroll
    for (int i = 0; i < 4; ++i) {
      float v = tile[tx][ty + i * 8];
      AT[(long)z * 524288 + (long)(c0 + ty + i * 8) * 512 + r0 + tx] = f2bf(v);
    }
  }
}

// z=0: W11 split straight; z=1: W12 transpose-split; z=2: W21T; z=3: W22T
__global__ __launch_bounds__(256) void prep_W(
    const float* __restrict__ W11, const float* __restrict__ W12,
    const float* __restrict__ W21, const float* __restrict__ W22,
    unsigned short* __restrict__ Wcat_hi, unsigned short* __restrict__ Wcat_lo,
    unsigned short* __restrict__ W21T, unsigned short* __restrict__ W22T)
{
  __shared__ float tile[32][33];
  int z = blockIdx.z;
  const float* src = z == 0 ? W11 : z == 1 ? W12 : z == 2 ? W21 : W22;
  int r0 = blockIdx.y * 32, c0 = blockIdx.x * 32;
  int tx = threadIdx.x, ty = threadIdx.y;
  #pragma unroll
  for (int i = 0; i < 4; ++i) {
    int r = r0 + ty + i * 8;
    float v = src[(long)r * 1024 + c0 + tx];
    tile[ty + i * 8][tx] = v;
    if (z == 0) {
      long o = (long)r * 1024 + c0 + tx;
      unsigned short h = f2bf(v);
      Wcat_hi[o] = h;
      Wcat_lo[o] = f2bf(v - bf2f(h));
    }
  }
  __syncthreads();
  if (z > 0) {
    #pragma unroll
    for (int i = 0; i < 4; ++i) {
      float v = tile[tx][ty + i * 8];
      long o = (long)(c0 + ty + i * 8) * 1024 + r0 + tx;
      unsigned short h = f2bf(v);
      if (z == 1) {
        Wcat_hi[1048576 + o] = h;
        Wcat_lo[1048576 + o] = f2bf(v - bf2f(h));
      } else if (z == 2) W21T[o] = h;
      else W22T[o] = h;
    }
  }
}

// ---------------- softmax (merged) + final ----------------

__global__ __launch_bounds__(256) void softmax_both(const float* __restrict__ S,
    unsigned short* __restrict__ aq, unsigned short* __restrict__ qa)
{
  if (blockIdx.x < 4096) {
    int row  = blockIdx.x * 4 + (threadIdx.x >> 6);
    int lane = threadIdx.x & 63;
    float v = S[(long)row * 128 + lane];
    float m = v;
    #pragma unroll
    for (int off = 32; off; off >>= 1) m = fmaxf(m, __shfl_xor(m, off));
    float e = __expf(v - m);
    float s = e;
    #pragma unroll
    for (int off = 32; off; off >>= 1) s += __shfl_xor(s, off);
    aq[(long)row * 64 + lane] = f2bf(e / s);
  } else {
    int bq = blockIdx.x - 4096;
    int b = bq >> 6, q = bq & 63;
    int t = threadIdx.x;
    const float* base = S + (long)b * 65536 + 64 + q;
    float v0 = base[(long)t * 128];
    float v1 = base[(long)(t + 256) * 128];
    float m = fmaxf(v0, v1);
    #pragma unroll
    for (int off = 32; off; off >>= 1) m = fmaxf(m, __shfl_xor(m, off));
    __shared__ float sm[4], ss[4];
    int wid = t >> 6, lane = t & 63;
    if (lane == 0) sm[wid] = m;
    __syncthreads();
    float M = fmaxf(fmaxf(sm[0], sm[1]), fmaxf(sm[2], sm[3]));
    float e0 = __expf(v0 - M), e1 = __expf(v1 - M);
    float s = e0 + e1;
    #pragma unroll
    for (int off = 32; off; off >>= 1) s += __shfl_xor(s, off);
    if (lane == 0) ss[wid] = s;
    __syncthreads();
    float inv = 1.0f / ((ss[0] + ss[1]) + (ss[2] + ss[3]));
    qa[(long)bq * 512 + t]       = f2bf(e0 * inv);
    qa[(long)bq * 512 + t + 256] = f2bf(e1 * inv);
  }
}

__global__ __launch_bounds__(256) void final_combine(
    const float* __restrict__ PmaxA, const float* __restrict__ PmaxQ, float* __restrict__ out)
{
  int idx = blockIdx.x * 256 + threadIdx.x;  // 32768
  int b = idx >> 10, h = idx & 1023;
  float m = PmaxA[(long)(b * 4) * 1024 + h];
  #pragma unroll
  for (int mt = 1; mt < 4; ++mt)
    m = fmaxf(m, PmaxA[(long)(b * 4 + mt) * 1024 + h]);
  out[idx] = 0.5f * m + 0.5f * PmaxQ[idx];
}

// ---------------- launch ----------------

extern "C" void kernel_launch(void* const* d_in, const int* in_sizes, int n_in,
                              void* d_out, int out_size, void* d_ws, size_t ws_size,
                              hipStream_t stream) {
  const float* Afeat = (const float*)d_in[0];
  const float* Qfeat = (const float*)d_in[1];
  const float* W11   = (const float*)d_in[2];
  const float* W12   = (const float*)d_in[3];
  const float* W21   = (const float*)d_in[4];
  const float* W22   = (const float*)d_in[5];
  float* out = (float*)d_out;

  char* w = (char*)d_ws;
  auto alloc = [&](long bytes) { char* p = w; w += bytes; return p; };
  unsigned short* A_hi    = (unsigned short*)alloc(33554432);
  unsigned short* A_lo    = (unsigned short*)alloc(33554432);
  unsigned short* AT      = (unsigned short*)alloc(33554432);  // [32][1024][512]
  unsigned short* Q_hi    = (unsigned short*)alloc(4194304);
  unsigned short* Q_lo    = (unsigned short*)alloc(4194304);
  unsigned short* Wcat_hi = (unsigned short*)alloc(4194304);   // [2048][1024]
  unsigned short* Wcat_lo = (unsigned short*)alloc(4194304);
  unsigned short* W21T    = (unsigned short*)alloc(2097152);
  unsigned short* W22T    = (unsigned short*)alloc(2097152);
  unsigned short* Pcat_hi = (unsigned short*)alloc(8388608);   // [32][128][1024]
  unsigned short* Pcat_lo = (unsigned short*)alloc(8388608);
  unsigned short* P3T     = (unsigned short*)alloc(4194304);   // [32][1024][64]
  float*          Spack   = (float*)alloc(8388608);            // [32][512][128]
  unsigned short* aq      = (unsigned short*)alloc(2097152);   // [32][512][64]
  unsigned short* qa      = (unsigned short*)alloc(2097152);   // [32][64][512]
  unsigned short* ctx     = (unsigned short*)alloc(4194304);   // [32][64][1024]
  float*          PmaxA   = (float*)alloc(524288);             // [128][1024]
  float*          PmaxQ   = (float*)alloc(131072);             // [32][1024]

  dim3 blk(256), tblk(32, 8);

  prep_A<<<dim3(32, 16, 36), tblk, 0, stream>>>(Afeat, Qfeat, A_hi, A_lo, AT, Q_hi, Q_lo);
  prep_W<<<dim3(32, 32, 4),  tblk, 0, stream>>>(W11, W12, W21, W22, Wcat_hi, Wcat_lo, W21T, W22T);

  g1_kernel<<<1024, blk, 0, stream>>>(Q_hi, Q_lo, Wcat_hi, Wcat_lo, W21T, Pcat_hi, Pcat_lo, P3T);
  g2_kernel<<<dim3(2, 8, 32), blk, 0, stream>>>(A_hi, A_lo, Pcat_hi, Pcat_lo, Spack);
  softmax_both<<<6144, blk, 0, stream>>>(Spack, aq, qa);
  g3_kernel<<<1536, blk, 0, stream>>>(aq, P3T, PmaxA, qa, AT, ctx);
  g4_kernel<<<dim3(16, 32), blk, 0, stream>>>(ctx, W22T, PmaxQ);
  final_combine<<<128, blk, 0, stream>>>(PmaxA, PmaxQ, out);
}

// Round 4
// 143.222 us; speedup vs baseline: 5.3257x; 1.0970x over previous
//
#include <hip/hip_runtime.h>
#include <stdint.h>

// B=32, La=512, Lq=64, H=1024. Score path split-bf16 (3 MFMA), value path bf16.
// prep: Q -> Q_hi/Q_lo (conv_split); W11/W12^T -> Wcat split; W21T, W22T (prep_W)
// g1: Pcat = Q(split)@Wcat^T (remap) || P3T = (Q@W21)^T
// g2: Spack scores = A(split fp32-staged)@Pcat^T, tile 64x128; fused aq row-softmax;
//     qa half written fp32 to Spack2
// softmax_cols: qa = colsoftmax(Spack2) bf16
// g3: PmaxA = colmax(relu(aq@P3T^T)) || ctx = qa@A (A fp32 transpose-staged)
// g4: PmaxQ = colmax64(relu(ctx@W22T^T))
// final: out = 0.5*max4(PmaxA) + 0.5*PmaxQ

using bf16x8 = __attribute__((ext_vector_type(8))) short;
using f32x4  = __attribute__((ext_vector_type(4))) float;
typedef const __attribute__((address_space(1))) void* gas_t;
typedef __attribute__((address_space(3))) void* las_t;

__device__ __forceinline__ unsigned short f2bf(float x) {
  unsigned u = __builtin_bit_cast(unsigned, x);
  u += 0x7fffu + ((u >> 16) & 1u);
  return (unsigned short)(u >> 16);
}
__device__ __forceinline__ float bf2f(unsigned short h) {
  unsigned u = ((unsigned)h) << 16;
  return __builtin_bit_cast(float, u);
}

// ---------------- prep ----------------

__global__ __launch_bounds__(256) void conv_split(const float* __restrict__ in,
    unsigned short* __restrict__ hi, unsigned short* __restrict__ lo, int n4)
{
  int i = blockIdx.x * 256 + threadIdx.x;
  if (i >= n4) return;
  float4 v = ((const float4*)in)[i];
  ushort4 h, l;
  h.x = f2bf(v.x); l.x = f2bf(v.x - bf2f(h.x));
  h.y = f2bf(v.y); l.y = f2bf(v.y - bf2f(h.y));
  h.z = f2bf(v.z); l.z = f2bf(v.z - bf2f(h.z));
  h.w = f2bf(v.w); l.w = f2bf(v.w - bf2f(h.w));
  ((ushort4*)hi)[i] = h;
  ((ushort4*)lo)[i] = l;
}

// z=0: W11 split straight; z=1: W12 transpose-split; z=2: W21T; z=3: W22T
__global__ __launch_bounds__(256) void prep_W(
    const float* __restrict__ W11, const float* __restrict__ W12,
    const float* __restrict__ W21, const float* __restrict__ W22,
    unsigned short* __restrict__ Wcat_hi, unsigned short* __restrict__ Wcat_lo,
    unsigned short* __restrict__ W21T, unsigned short* __restrict__ W22T)
{
  __shared__ float tile[32][33];
  int z = blockIdx.z;
  const float* src = z == 0 ? W11 : z == 1 ? W12 : z == 2 ? W21 : W22;
  int r0 = blockIdx.y * 32, c0 = blockIdx.x * 32;
  int tx = threadIdx.x, ty = threadIdx.y;
  #pragma unroll
  for (int i = 0; i < 4; ++i) {
    int r = r0 + ty + i * 8;
    float v = src[(long)r * 1024 + c0 + tx];
    tile[ty + i * 8][tx] = v;
    if (z == 0) {
      long o = (long)r * 1024 + c0 + tx;
      unsigned short h = f2bf(v);
      Wcat_hi[o] = h;
      Wcat_lo[o] = f2bf(v - bf2f(h));
    }
  }
  __syncthreads();
  if (z > 0) {
    #pragma unroll
    for (int i = 0; i < 4; ++i) {
      float v = tile[tx][ty + i * 8];
      long o = (long)(c0 + ty + i * 8) * 1024 + r0 + tx;
      unsigned short h = f2bf(v);
      if (z == 1) {
        Wcat_hi[1048576 + o] = h;
        Wcat_lo[1048576 + o] = f2bf(v - bf2f(h));
      } else if (z == 2) W21T[o] = h;
      else W22T[o] = h;
    }
  }
}

// ---------------- generic MFMA GEMM body (C = A @ B^T) ----------------
// OUT: 1=Pcat split remap, 2=bf16 (row<M), 3=P3T transpose, 4=relu+colmax(BM),
// 5=relu+colmax per 64 rows. BF32: B operand is fp32 [K x ldB] (transpose-staged).
template<int BM, int BN, bool SPLIT, int OUT, bool BF32>
__device__ __forceinline__ void gemm_body(
    char* smem, int bx, int by, int z,
    const unsigned short* __restrict__ Ah, const unsigned short* __restrict__ Al,
    const unsigned short* __restrict__ Bh, const unsigned short* __restrict__ Bl,
    const float* __restrict__ Bf,
    float* __restrict__ Cf, unsigned short* __restrict__ Ch, unsigned short* __restrict__ Cl,
    int M, int N, int K, int ldA, int ldB, int ldC, long sA, long sB, long sC, int mtiles)
{
  constexpr int AB = BM * 64, BB = BN * 64;
  constexpr int MI = BM / 32, NI = BN / 32;
  char* As  = smem;
  char* Asl = SPLIT ? smem + AB : nullptr;
  char* Bs  = smem + (SPLIT ? 2 * AB : AB);
  char* Bsl = SPLIT ? Bs + BB : nullptr;

  const int m0 = by * BM, n0 = bx * BN;
  const int t = threadIdx.x, lane = t & 63;
  const int wid = t >> 6, wr = wid >> 1, wc = wid & 1;

  const unsigned short* Ab  = Ah + (long)z * sA;
  const unsigned short* Bb  = BF32 ? nullptr : Bh + (long)z * sB;
  const unsigned short* Abl = SPLIT ? Al + (long)z * sA : nullptr;
  const unsigned short* Bbl = SPLIT ? Bl + (long)z * sB : nullptr;
  const float* Bfb = BF32 ? Bf + (long)z * sB : nullptr;

  f32x4 acc[MI][NI];
  #pragma unroll
  for (int i = 0; i < MI; ++i)
    #pragma unroll
    for (int j = 0; j < NI; ++j)
      acc[i][j] = f32x4{0.f, 0.f, 0.f, 0.f};

  auto stage4k = [&](char* lbuf, const unsigned short* g, int ld, int row0, int k0, int rmax) {
    int ob = t * 16;
    int e  = ob ^ (((ob >> 7) & 3) << 4);
    int m  = e >> 6, k = (e & 63) >> 1;
    int row = row0 + m; row = row < rmax ? row : rmax - 1;
    const unsigned short* gp = g + (long)row * ld + k0 + k;
    char* lp = lbuf + (t & ~63) * 16;  // wave-uniform; HW adds lane*16
    __builtin_amdgcn_global_load_lds((gas_t)(const void*)gp, (las_t)(void*)lp, 16, 0, 0);
  };
  // B tile [BN n x 32 k] from fp32 source B[k, n] (k-major): transpose + convert
  auto stageB_f32 = [&](char* lbuf, const float* g, int ld, int nb, int k0) {
    int ob = t * 16;
    int e  = ob ^ (((ob >> 7) & 3) << 4);
    int n  = e >> 6, kb = (e & 63) >> 1;
    bf16x8 pk;
    #pragma unroll
    for (int j = 0; j < 8; ++j) {
      float v = g[(long)(k0 + kb + j) * ld + nb + n];
      pk[j] = (short)f2bf(v);
    }
    *(bf16x8*)(lbuf + ob) = pk;
  };
  auto ldfrag = [&](const char* lbuf, int rr) -> bf16x8 {
    int ob = rr * 64 + (lane >> 4) * 16;
    ob ^= ((ob >> 7) & 3) << 4;
    return *(const bf16x8*)(lbuf + ob);
  };

  for (int k0 = 0; k0 < K; k0 += 32) {
    stage4k(As, Ab, ldA, m0, k0, M);
    if (BM == 128) stage4k(As + 4096, Ab, ldA, m0 + 64, k0, M);
    if (BF32) {
      stageB_f32(Bs, Bfb, ldB, n0, k0);
    } else {
      stage4k(Bs, Bb, ldB, n0, k0, N);
      if (BN == 128) stage4k(Bs + 4096, Bb, ldB, n0 + 64, k0, N);
    }
    if (SPLIT) {
      stage4k(Asl, Abl, ldA, m0, k0, M);
      if (BM == 128) stage4k(Asl + 4096, Abl, ldA, m0 + 64, k0, M);
      stage4k(Bsl, Bbl, ldB, n0, k0, N);
      if (BN == 128) stage4k(Bsl + 4096, Bbl, ldB, n0 + 64, k0, N);
    }
    __syncthreads();

    bf16x8 ah[MI], al[MI];
    #pragma unroll
    for (int mi = 0; mi < MI; ++mi) {
      int rr = wr * (BM / 2) + mi * 16 + (lane & 15);
      ah[mi] = ldfrag(As, rr);
      if (SPLIT) al[mi] = ldfrag(Asl, rr);
    }
    #pragma unroll
    for (int ni = 0; ni < NI; ++ni) {
      int rc = wc * (BN / 2) + ni * 16 + (lane & 15);
      bf16x8 bh = ldfrag(Bs, rc);
      bf16x8 bl;
      if (SPLIT) bl = ldfrag(Bsl, rc);
      #pragma unroll
      for (int mi = 0; mi < MI; ++mi) {
        acc[mi][ni] = __builtin_amdgcn_mfma_f32_16x16x32_bf16(ah[mi], bh, acc[mi][ni], 0, 0, 0);
        if (SPLIT) {
          acc[mi][ni] = __builtin_amdgcn_mfma_f32_16x16x32_bf16(ah[mi], bl, acc[mi][ni], 0, 0, 0);
          acc[mi][ni] = __builtin_amdgcn_mfma_f32_16x16x32_bf16(al[mi], bh, acc[mi][ni], 0, 0, 0);
        }
      }
    }
    __syncthreads();
  }

  if (OUT == 4 || OUT == 5) {
    float* red = (float*)smem;
    #pragma unroll
    for (int ni = 0; ni < NI; ++ni) {
      float pm = 0.0f;  // relu floor
      #pragma unroll
      for (int mi = 0; mi < MI; ++mi)
        #pragma unroll
        for (int r = 0; r < 4; ++r)
          pm = fmaxf(pm, acc[mi][ni][r]);
      int g = wr * 4 + (lane >> 4);
      int col = wc * (BN / 2) + ni * 16 + (lane & 15);
      red[g * BN + col] = pm;
    }
    __syncthreads();
    if (OUT == 4) {
      if (t < BN) {
        float m = red[t];
        #pragma unroll
        for (int g = 1; g < 8; ++g) m = fmaxf(m, red[g * BN + t]);
        Cf[(long)(z * mtiles + by) * ldC + n0 + t] = m;
      }
    } else {
      constexpr int NGR = BM / 64, PG = 8 / NGR;
      if (t < NGR * BN) {
        int hh = t / BN, col = t - hh * BN;
        float m = red[(hh * PG) * BN + col];
        #pragma unroll
        for (int i = 1; i < PG; ++i) m = fmaxf(m, red[(hh * PG + i) * BN + col]);
        Cf[(long)((m0 >> 6) + hh) * ldC + n0 + col] = m;
      }
    }
    return;
  }

  #pragma unroll
  for (int mi = 0; mi < MI; ++mi) {
    #pragma unroll
    for (int r = 0; r < 4; ++r) {
      int grow = m0 + wr * (BM / 2) + mi * 16 + (lane >> 4) * 4 + r;
      #pragma unroll
      for (int ni = 0; ni < NI; ++ni) {
        int gcol = n0 + wc * (BN / 2) + ni * 16 + (lane & 15);
        float v = acc[mi][ni][r];
        if (OUT == 1) {
          int b = grow >> 6, q = grow & 63;
          long dst = (long)b * 131072 + (long)((gcol >> 10) * 64 + q) * 1024 + (gcol & 1023);
          unsigned short h = f2bf(v);
          Ch[dst] = h;
          Cl[dst] = f2bf(v - bf2f(h));
        } else if (OUT == 2) {
          if (grow < M) Ch[(long)z * sC + (long)grow * ldC + gcol] = f2bf(v);
        } else if (OUT == 3) {
          long dst = (long)(grow >> 6) * 65536 + (long)gcol * 64 + (grow & 63);
          Ch[dst] = f2bf(v);
        }
      }
    }
  }
}

// ---------------- g1: Pcat || P3T ----------------

__global__ __launch_bounds__(256) void g1_kernel(
    const unsigned short* Q_hi, const unsigned short* Q_lo,
    const unsigned short* Wcat_hi, const unsigned short* Wcat_lo,
    const unsigned short* W21T,
    unsigned short* Pcat_hi, unsigned short* Pcat_lo, unsigned short* P3T)
{
  __shared__ char smem[24576];
  int bid = blockIdx.x;
  if (bid < 512) {   // Pcat: M=2048,N=2048,K=1024, tile 128x64
    gemm_body<128, 64, true, 1, false>(smem, bid & 31, bid >> 5, 0,
        Q_hi, Q_lo, Wcat_hi, Wcat_lo, nullptr, nullptr, Pcat_hi, Pcat_lo,
        2048, 2048, 1024, 1024, 1024, 0, 0, 0, 0, 0);
  } else {           // P3T: M=2048,N=1024,K=1024, tile 64x64
    int b2 = bid - 512;
    gemm_body<64, 64, false, 3, false>(smem, b2 & 15, b2 >> 4, 0,
        Q_hi, nullptr, W21T, nullptr, nullptr, nullptr, P3T, nullptr,
        2048, 1024, 1024, 1024, 1024, 0, 0, 0, 0, 0);
  }
}

// ---------------- g2: scores with fused A-split staging + aq softmax ----------------
// tile 64x128, 8 waves (4 m-rows x 2 n-cols), grid 256 blocks (chunked z->XCD).

__global__ __launch_bounds__(512) void g2_kernel(
    const float* __restrict__ Afeat,
    const unsigned short* __restrict__ Pcat_hi, const unsigned short* __restrict__ Pcat_lo,
    unsigned short* __restrict__ aq, float* __restrict__ Spack2)
{
  __shared__ char smem[24576];
  char* Ash = smem;           // 4KB
  char* Asl = smem + 4096;    // 4KB
  char* Bs  = smem + 8192;    // 8KB
  char* Bsl = smem + 16384;   // 8KB

  int orig = blockIdx.x;
  int xcd = orig & 7, idx = orig >> 3;
  int z  = xcd * 4 + (idx >> 3);   // 4 batches per XCD -> Pcat L2-resident
  int by = idx & 7;
  const int m0 = by * 64;
  const int t = threadIdx.x, lane = t & 63;
  const int wid = t >> 6, wr = wid >> 1, wc = wid & 1;

  const float* Ab = Afeat + (long)z * 524288;
  const unsigned short* Bbh = Pcat_hi + (long)z * 131072;
  const unsigned short* Bbl = Pcat_lo + (long)z * 131072;

  f32x4 acc[4];
  #pragma unroll
  for (int i = 0; i < 4; ++i) acc[i] = f32x4{0.f, 0.f, 0.f, 0.f};

  auto ldfrag = [&](const char* lbuf, int rr) -> bf16x8 {
    int ob = rr * 64 + (lane >> 4) * 16;
    ob ^= ((ob >> 7) & 3) << 4;
    return *(const bf16x8*)(lbuf + ob);
  };

  for (int k0 = 0; k0 < 1024; k0 += 32) {
    { // A: fp32 load + split + ds_write (8B hi + 8B lo per thread)
      int ob = t * 8;
      int e  = ob ^ (((ob >> 7) & 3) << 4);
      int m  = e >> 6, ke = (e & 63) >> 1;
      float4 v = *(const float4*)(Ab + (long)(m0 + m) * 1024 + k0 + ke);
      ushort4 h, l;
      h.x = f2bf(v.x); l.x = f2bf(v.x - bf2f(h.x));
      h.y = f2bf(v.y); l.y = f2bf(v.y - bf2f(h.y));
      h.z = f2bf(v.z); l.z = f2bf(v.z - bf2f(h.z));
      h.w = f2bf(v.w); l.w = f2bf(v.w - bf2f(h.w));
      *(ushort4*)(Ash + ob) = h;
      *(ushort4*)(Asl + ob) = l;
    }
    { // B: gload hi+lo, 8KB each (512 threads x 16B)
      int ob = t * 16;
      int e  = ob ^ (((ob >> 7) & 3) << 4);
      int n  = e >> 6, kk = (e & 63) >> 1;
      const unsigned short* gp  = Bbh + (long)n * 1024 + k0 + kk;
      const unsigned short* gpl = Bbl + (long)n * 1024 + k0 + kk;
      char* lp  = Bs  + (t & ~63) * 16;
      char* lpl = Bsl + (t & ~63) * 16;
      __builtin_amdgcn_global_load_lds((gas_t)(const void*)gp,  (las_t)(void*)lp,  16, 0, 0);
      __builtin_amdgcn_global_load_lds((gas_t)(const void*)gpl, (las_t)(void*)lpl, 16, 0, 0);
    }
    __syncthreads();

    bf16x8 ah = ldfrag(Ash, wr * 16 + (lane & 15));
    bf16x8 al = ldfrag(Asl, wr * 16 + (lane & 15));
    #pragma unroll
    for (int ni = 0; ni < 4; ++ni) {
      bf16x8 bh = ldfrag(Bs,  wc * 64 + ni * 16 + (lane & 15));
      bf16x8 bl = ldfrag(Bsl, wc * 64 + ni * 16 + (lane & 15));
      acc[ni] = __builtin_amdgcn_mfma_f32_16x16x32_bf16(ah, bh, acc[ni], 0, 0, 0);
      acc[ni] = __builtin_amdgcn_mfma_f32_16x16x32_bf16(ah, bl, acc[ni], 0, 0, 0);
      acc[ni] = __builtin_amdgcn_mfma_f32_16x16x32_bf16(al, bh, acc[ni], 0, 0, 0);
    }
    __syncthreads();
  }

  // epilogue: wc=0 waves hold aq scores (cols 0..63) -> fused row softmax;
  // wc=1 waves hold qa scores (cols 64..127) -> Spack2 fp32.
  #pragma unroll
  for (int r = 0; r < 4; ++r) {
    int grow = m0 + wr * 16 + (lane >> 4) * 4 + r;
    long base = (long)z * 32768 + (long)grow * 64 + (lane & 15);
    float v0 = acc[0][r], v1 = acc[1][r], v2 = acc[2][r], v3 = acc[3][r];
    if (wc == 0) {
      float mx = fmaxf(fmaxf(v0, v1), fmaxf(v2, v3));
      #pragma unroll
      for (int off = 8; off; off >>= 1) mx = fmaxf(mx, __shfl_xor(mx, off));
      float e0 = __expf(v0 - mx), e1 = __expf(v1 - mx);
      float e2 = __expf(v2 - mx), e3 = __expf(v3 - mx);
      float s = (e0 + e1) + (e2 + e3);
      #pragma unroll
      for (int off = 8; off; off >>= 1) s += __shfl_xor(s, off);
      float inv = 1.0f / s;
      aq[base]      = f2bf(e0 * inv);
      aq[base + 16] = f2bf(e1 * inv);
      aq[base + 32] = f2bf(e2 * inv);
      aq[base + 48] = f2bf(e3 * inv);
    } else {
      Spack2[base]      = v0;
      Spack2[base + 16] = v1;
      Spack2[base + 32] = v2;
      Spack2[base + 48] = v3;
    }
  }
}

// ---------------- qa col-softmax ----------------

__global__ __launch_bounds__(256) void softmax_cols(const float* __restrict__ S2,
                                                    unsigned short* __restrict__ qa)
{
  int bq = blockIdx.x;
  int b = bq >> 6, q = bq & 63;
  int t = threadIdx.x;
  const float* base = S2 + (long)b * 32768 + q;
  float v0 = base[(long)t * 64];
  float v1 = base[(long)(t + 256) * 64];
  float m = fmaxf(v0, v1);
  #pragma unroll
  for (int off = 32; off; off >>= 1) m = fmaxf(m, __shfl_xor(m, off));
  __shared__ float sm[4], ss[4];
  int wid = t >> 6, lane = t & 63;
  if (lane == 0) sm[wid] = m;
  __syncthreads();
  float M = fmaxf(fmaxf(sm[0], sm[1]), fmaxf(sm[2], sm[3]));
  float e0 = __expf(v0 - M), e1 = __expf(v1 - M);
  float s = e0 + e1;
  #pragma unroll
  for (int off = 32; off; off >>= 1) s += __shfl_xor(s, off);
  if (lane == 0) ss[wid] = s;
  __syncthreads();
  float inv = 1.0f / ((ss[0] + ss[1]) + (ss[2] + ss[3]));
  qa[(long)bq * 512 + t]       = f2bf(e0 * inv);
  qa[(long)bq * 512 + t + 256] = f2bf(e1 * inv);
}

// ---------------- g3: PmaxA || ctx ----------------

__global__ __launch_bounds__(256) void g3_kernel(
    const unsigned short* aq, const unsigned short* P3T, float* PmaxA,
    const unsigned short* qa, const float* Afeat, unsigned short* ctx)
{
  __shared__ char smem[16384];
  int bid = blockIdx.x;
  if (bid < 1024) {  // PmaxA: per batch M=512,N=1024,K=64, tile 128x128
    gemm_body<128, 128, false, 4, false>(smem, bid & 7, (bid >> 3) & 3, bid >> 5,
        aq, nullptr, P3T, nullptr, nullptr, PmaxA, nullptr, nullptr,
        512, 1024, 64, 64, 64, 1024, 32768L, 65536L, 0, 4);
  } else {           // ctx: per batch M=64,N=1024,K=512, tile 64x64, B = A fp32 (k-major)
    int b2 = bid - 1024;
    gemm_body<64, 64, false, 2, true>(smem, b2 & 15, 0, b2 >> 4,
        qa, nullptr, nullptr, nullptr, Afeat, nullptr, ctx, nullptr,
        64, 1024, 512, 512, 1024, 1024, 32768L, 524288L, 65536L, 0);
  }
}

// ---------------- g4 + final ----------------

__global__ __launch_bounds__(256) void g4_kernel(
    const unsigned short* ctx, const unsigned short* W22T, float* PmaxQ)
{
  __shared__ char smem[8192];
  gemm_body<64, 64, false, 5, false>(smem, blockIdx.x, blockIdx.y, 0,
      ctx, nullptr, W22T, nullptr, nullptr, PmaxQ, nullptr, nullptr,
      2048, 1024, 1024, 1024, 1024, 1024, 0, 0, 0, 0);
}

__global__ __launch_bounds__(256) void final_combine(
    const float* __restrict__ PmaxA, const float* __restrict__ PmaxQ, float* __restrict__ out)
{
  int idx = blockIdx.x * 256 + threadIdx.x;  // 32768
  int b = idx >> 10, h = idx & 1023;
  float m = PmaxA[(long)(b * 4) * 1024 + h];
  #pragma unroll
  for (int mt = 1; mt < 4; ++mt)
    m = fmaxf(m, PmaxA[(long)(b * 4 + mt) * 1024 + h]);
  out[idx] = 0.5f * m + 0.5f * PmaxQ[idx];
}

// ---------------- launch ----------------

extern "C" void kernel_launch(void* const* d_in, const int* in_sizes, int n_in,
                              void* d_out, int out_size, void* d_ws, size_t ws_size,
                              hipStream_t stream) {
  const float* Afeat = (const float*)d_in[0];
  const float* Qfeat = (const float*)d_in[1];
  const float* W11   = (const float*)d_in[2];
  const float* W12   = (const float*)d_in[3];
  const float* W21   = (const float*)d_in[4];
  const float* W22   = (const float*)d_in[5];
  float* out = (float*)d_out;

  char* w = (char*)d_ws;
  auto alloc = [&](long bytes) { char* p = w; w += bytes; return p; };
  unsigned short* Q_hi    = (unsigned short*)alloc(4194304);
  unsigned short* Q_lo    = (unsigned short*)alloc(4194304);
  unsigned short* Wcat_hi = (unsigned short*)alloc(4194304);   // [2048][1024]
  unsigned short* Wcat_lo = (unsigned short*)alloc(4194304);
  unsigned short* W21T    = (unsigned short*)alloc(2097152);
  unsigned short* W22T    = (unsigned short*)alloc(2097152);
  unsigned short* Pcat_hi = (unsigned short*)alloc(8388608);   // [32][128][1024]
  unsigned short* Pcat_lo = (unsigned short*)alloc(8388608);
  unsigned short* P3T     = (unsigned short*)alloc(4194304);   // [32][1024][64]
  float*          Spack2  = (float*)alloc(4194304);            // [32][512][64]
  unsigned short* aq      = (unsigned short*)alloc(2097152);   // [32][512][64]
  unsigned short* qa      = (unsigned short*)alloc(2097152);   // [32][64][512]
  unsigned short* ctx     = (unsigned short*)alloc(4194304);   // [32][64][1024]
  float*          PmaxA   = (float*)alloc(524288);             // [128][1024]
  float*          PmaxQ   = (float*)alloc(131072);             // [32][1024]

  dim3 blk(256), tblk(32, 8);

  conv_split<<<2048, blk, 0, stream>>>(Qfeat, Q_hi, Q_lo, 524288);
  prep_W<<<dim3(32, 32, 4), tblk, 0, stream>>>(W11, W12, W21, W22, Wcat_hi, Wcat_lo, W21T, W22T);

  g1_kernel<<<1024, blk, 0, stream>>>(Q_hi, Q_lo, Wcat_hi, Wcat_lo, W21T, Pcat_hi, Pcat_lo, P3T);
  g2_kernel<<<256, dim3(512), 0, stream>>>(Afeat, Pcat_hi, Pcat_lo, aq, Spack2);
  softmax_cols<<<2048, blk, 0, stream>>>(Spack2, qa);
  g3_kernel<<<1536, blk, 0, stream>>>(aq, P3T, PmaxA, qa, Afeat, ctx);
  g4_kernel<<<dim3(16, 32), blk, 0, stream>>>(ctx, W22T, PmaxQ);
  final_combine<<<128, blk, 0, stream>>>(PmaxA, PmaxQ, out);
}